// Round 1
// baseline (69.357 us; speedup 1.0000x reference)
//
#include <hip/hip_runtime.h>

// AdderNet 2D: out[n,f,h,w] = -sum_{c,kh,kw} |W[f,c,kh,kw] - xpad[n,c,h+kh,w+kw]|
// x: (16,64,14,14) fp32, W: (64,64,3,3) fp32, out: (16,64,14,14) fp32
//
// R10: single-kernel FULL channel reduction -> no hipMemsetAsync dispatch, no
// global atomics (R9 split C over 4 blocks and met at atomicAdd on a zeroed
// buffer; that cost a second graph node + 200K 4-way-conflicting f32 atomics).
// Each wave now owns 16 channels as 4 quads; W is reloaded per quad (36 VGPRs
// live, constant-indexed, fully unrolled -> no scratch demotion, the exact
// codegen idiom proven in R9). To keep occupancy after 4x'ing per-thread work,
// the 14 output cols split into two 7-col halves: grid (14,16,2) = 448 blocks,
// __launch_bounds__(256,2) caps VGPR at 256 -> 2 blocks/CU where scheduled.
// x rows still come from LDS via wave-uniform ds_read_b128 broadcasts
// (conflict-free, immediate offsets) -- R6-R8 proved direct global/K$ reads
// are the 9x wall. Partials stride 9 (odd) -> conflict-free LDS reduce,
// plain coalesced stores.

#define N_ 16
#define C_ 64
#define F_ 64
#define P_ 196

__global__ __launch_bounds__(256, 2) void adder2d_kernel(
    const float* __restrict__ x, const float* __restrict__ w,
    float* __restrict__ out)
{
    // [c(64)][r(3)][col(12, zero-padded window)] = 2304 floats = 9 KB
    __shared__ __align__(16) float xs[64 * 36];
    __shared__ float part[4][64 * 9];   // stride 9 -> conflict-free

    const int tid = threadIdx.x;        // 0..255
    const int row = blockIdx.x;         // 0..13 output row
    const int n   = blockIdx.y;         // 0..15
    const int z   = blockIdx.z;         // 0..1 column half (cols z*7 .. z*7+6)
    const int f   = tid & 63;           // lane = filter
    const int wid = tid >> 6;           // wave 0..3 -> 16-channel slice

    // ---- stage 64ch x 3 rows x 12 padded cols: 9 stores/thr ----
    // staged col j == padded col z*7 + j == input col z*7 + j - 1
    #pragma unroll
    for (int i = 0; i < 9; ++i) {
        const int idx = tid + 256 * i;          // 0..2303
        const int c   = idx / 36;
        const int rem = idx - c * 36;
        const int r   = rem / 12;               // 0..2
        const int j   = rem - r * 12;           // 0..11
        const int ir  = row + r - 1;            // input row, -1..14
        const int ic  = z * 7 + j - 1;          // input col
        float v = 0.f;
        if (ic >= 0 && ic <= 13 && ir >= 0 && ir <= 13)
            v = x[(n * C_ + c) * P_ + ir * 14 + ic];
        xs[idx] = v;
    }

    float acc[7];
    #pragma unroll
    for (int p = 0; p < 7; ++p) acc[p] = 0.f;

    __syncthreads();

    // ---- hot loop: 4 quads x (9 dwordx4 W-load + 12 sections of
    //      (3 ds_read_b128 broadcast + 42 VALU)) ----
    #pragma unroll
    for (int q = 0; q < 4; ++q) {
        const int cb = wid * 16 + q * 4;        // this wave's channel quad
        float Wr[36];
        {
            const float4* wp = (const float4*)(w + f * (C_ * 9) + cb * 9);
            #pragma unroll
            for (int i = 0; i < 9; ++i) {
                float4 t = wp[i];
                Wr[4 * i + 0] = t.x; Wr[4 * i + 1] = t.y;
                Wr[4 * i + 2] = t.z; Wr[4 * i + 3] = t.w;
            }
        }
        const float* xb = xs + cb * 36;
        #pragma unroll
        for (int cl = 0; cl < 4; ++cl) {
            #pragma unroll
            for (int kh = 0; kh < 3; ++kh) {
                const float4* rp = (const float4*)(xb + cl * 36 + kh * 12);
                float4 a0 = rp[0], a1 = rp[1], a2 = rp[2];
                float xr[12] = {a0.x, a0.y, a0.z, a0.w,
                                a1.x, a1.y, a1.z, a1.w,
                                a2.x, a2.y, a2.z, a2.w};
                #pragma unroll
                for (int kw = 0; kw < 3; ++kw) {
                    const float wv = Wr[cl * 9 + kh * 3 + kw]; // const index
                    #pragma unroll
                    for (int p = 0; p < 7; ++p)
                        acc[p] += fabsf(wv - xr[p + kw]);      // sub + add|.|
                }
            }
        }
    }

    // ---- 4-wave partial reduce in LDS (stride 9, conflict-free) ----
    #pragma unroll
    for (int p = 0; p < 7; ++p) part[wid][f * 9 + p] = acc[p];
    __syncthreads();

    // ---- 448 outputs this block; plain coalesced stores, no atomics ----
    for (int o = tid; o < 448; o += 256) {
        const int ff = o / 7;
        const int px = o - ff * 7;
        const int a  = ff * 9 + px;
        float s = part[0][a] + part[1][a] + part[2][a] + part[3][a];
        out[(n * F_ + ff) * P_ + row * 14 + z * 7 + px] = -s;
    }
}

extern "C" void kernel_launch(void* const* d_in, const int* in_sizes, int n_in,
                              void* d_out, int out_size, void* d_ws, size_t ws_size,
                              hipStream_t stream) {
    const float* x = (const float*)d_in[0];
    const float* w = (const float*)d_in[1];
    float* out = (float*)d_out;
    dim3 grid(14, N_, 2);
    adder2d_kernel<<<grid, 256, 0, stream>>>(x, w, out);
}